// Round 6
// baseline (1996.377 us; speedup 1.0000x reference)
//
#include <hip/hip_runtime.h>
#include <hip/hip_bf16.h>

// GASTLCModel: 4-layer GCN (tanh) -> SortPool top-64/graph -> conv5(k=385,s=385)
// -> maxpool2 -> conv6(k=5) -> FC(39424->128) -> FC(128->10).
// Float dtype (fp32 vs bf16) detected at runtime; all compute fp32.
// R6: 512B-align H buffers (rows were straddling 5 cache lines -> 25% HBM
// over-fetch); non-temporal stores for X streams + NT loads for GEMM streaming
// reads so L3 retains the gather-target H array (it fits: 205 MB < 256 MB L3).

#define NN 400000
#define EE 1600000
#define GG 11
#define DCAT 385
#define CCAP 40960

typedef float f32x4 __attribute__((ext_vector_type(4)));
typedef unsigned short u16x4 __attribute__((ext_vector_type(4)));

__device__ __forceinline__ float us2f(unsigned short u) {
    return __uint_as_float(((unsigned)u) << 16);
}
__device__ __forceinline__ float ldf(const void* p, long i, int dt) {
    return dt ? ((const float*)p)[i] : us2f(((const unsigned short*)p)[i]);
}
__device__ __forceinline__ unsigned fkey(float s) {
    unsigned u = __float_as_uint(s);
    return (u & 0x80000000u) ? ~u : (u | 0x80000000u);
}
__device__ __forceinline__ f32x4 ntld4(const float* p) {
    return __builtin_nontemporal_load((const f32x4*)p);
}
__device__ __forceinline__ u16x4 ntld4u(const unsigned short* p) {
    return __builtin_nontemporal_load((const u16x4*)p);
}
__device__ __forceinline__ void ntst4(float* p, f32x4 v) {
    __builtin_nontemporal_store(v, (f32x4*)p);
}

// ---------------- dtype detect: dt=1 fp32, dt=0 bf16 ----------------
__global__ void k_detect(const unsigned int* __restrict__ xw, int* __restrict__ flag) {
    if (threadIdx.x == 0) {
        int good = 0;
        for (int i = 0; i < 64; ++i) {
            float a = fabsf(us2f((unsigned short)(xw[i] & 0xffffu)));
            if (a > 0.004f && a < 16.f) ++good;
        }
        *flag = (good >= 32) ? 0 : 1;
    }
}

// ---------------- CSR build ----------------
__global__ void k_deg(const int* __restrict__ ei, int* __restrict__ degcnt) {
    int e = blockIdx.x * 256 + threadIdx.x;
    if (e >= EE) return;
    int s = ei[e], d = ei[EE + e];
    if (s != d) atomicAdd(&degcnt[d], 1);
}

__global__ void k_dis(const int* __restrict__ degcnt, float* __restrict__ dis) {
    int i = blockIdx.x * 256 + threadIdx.x;
    if (i < NN) dis[i] = 1.0f / sqrtf((float)degcnt[i] + 1.0f);
}

__global__ __launch_bounds__(256) void k_scan1(const int* __restrict__ in,
                                               int* __restrict__ out1,
                                               int* __restrict__ bsums, int n) {
    __shared__ int lds[256];
    int tid = threadIdx.x;
    int base = blockIdx.x * 1024 + tid * 4;
    int v0 = (base + 0 < n) ? in[base + 0] : 0;
    int v1 = (base + 1 < n) ? in[base + 1] : 0;
    int v2 = (base + 2 < n) ? in[base + 2] : 0;
    int v3 = (base + 3 < n) ? in[base + 3] : 0;
    v1 += v0; v2 += v1; v3 += v2;
    lds[tid] = v3;
    __syncthreads();
    for (int off = 1; off < 256; off <<= 1) {
        int x = (tid >= off) ? lds[tid - off] : 0;
        __syncthreads();
        lds[tid] += x;
        __syncthreads();
    }
    int prefix = (tid > 0) ? lds[tid - 1] : 0;
    if (base + 0 < n) out1[base + 0] = prefix + v0;
    if (base + 1 < n) out1[base + 1] = prefix + v1;
    if (base + 2 < n) out1[base + 2] = prefix + v2;
    if (base + 3 < n) out1[base + 3] = prefix + v3;
    if (tid == 255) bsums[blockIdx.x] = lds[255];
}

__global__ __launch_bounds__(512) void k_scan2(int* __restrict__ bsums, int nb) {
    __shared__ int lds[512];
    int tid = threadIdx.x;
    lds[tid] = (tid < nb) ? bsums[tid] : 0;
    __syncthreads();
    for (int off = 1; off < 512; off <<= 1) {
        int x = (tid >= off) ? lds[tid - off] : 0;
        __syncthreads();
        lds[tid] += x;
        __syncthreads();
    }
    int ex = (tid > 0) ? lds[tid - 1] : 0;
    if (tid < nb) bsums[tid] = ex;
}

__global__ void k_scan3(int* __restrict__ rowptr, const int* __restrict__ bsums, int n) {
    int i = blockIdx.x * 256 + threadIdx.x;
    if (i < n) rowptr[i + 1] += bsums[i >> 10];
    if (i == 0) rowptr[0] = 0;
}

__global__ void k_fill(const int* __restrict__ ei, const int* __restrict__ rowptr,
                       int* __restrict__ fill, int* __restrict__ col) {
    int e = blockIdx.x * 256 + threadIdx.x;
    if (e >= EE) return;
    int s = ei[e], d = ei[EE + e];
    if (s != d) {
        int p = atomicAdd(&fill[d], 1);
        col[rowptr[d] + p] = s;
    }
}

// ---- shared GEMM inner: acc[8][8] += a[8][4] (x) wlds[(k+j)*128 + c0/(+64)] ----
__device__ __forceinline__ void mm_inner(const float (&a)[8][4],
                                         const float* __restrict__ wlds, int k,
                                         int c0, float (&acc)[8][8]) {
#pragma unroll
    for (int j = 0; j < 4; j++) {
        float4 b0 = *(const float4*)&wlds[(k + j) * 128 + c0];
        float4 b1 = *(const float4*)&wlds[(k + j) * 128 + c0 + 64];
#pragma unroll
        for (int i = 0; i < 8; i++) {
            float av = a[i][j];
            acc[i][0] = fmaf(av, b0.x, acc[i][0]);
            acc[i][1] = fmaf(av, b0.y, acc[i][1]);
            acc[i][2] = fmaf(av, b0.z, acc[i][2]);
            acc[i][3] = fmaf(av, b0.w, acc[i][3]);
            acc[i][4] = fmaf(av, b1.x, acc[i][4]);
            acc[i][5] = fmaf(av, b1.y, acc[i][5]);
            acc[i][6] = fmaf(av, b1.z, acc[i][6]);
            acc[i][7] = fmaf(av, b1.w, acc[i][7]);
        }
    }
}

// --------- layer-1 GEMM: H = x @ W1 (100 x 128), dtype-adaptive ---------
__global__ __launch_bounds__(256, 2) void k_mm1(const void* __restrict__ Xin_,
                                                const void* __restrict__ W,
                                                const int* __restrict__ flag,
                                                float* __restrict__ H) {
    __shared__ float wlds[100 * 128];
    const int dt = *flag;
    const int tid = threadIdx.x;
    if (dt) {
        const float* Wf = (const float*)W;
        for (int idx = tid; idx < 100 * 128; idx += 256) wlds[idx] = Wf[idx];
    } else {
        const unsigned short* Wb = (const unsigned short*)W;
        for (int idx = tid; idx < 100 * 128; idx += 256) wlds[idx] = us2f(Wb[idx]);
    }
    __syncthreads();
    const int tx = tid & 15, ty = tid >> 4;
    const int c0 = tx * 4;
    const size_t r0 = (size_t)blockIdx.x * 128 + (size_t)ty * 8;
    float acc[8][8];
#pragma unroll
    for (int i = 0; i < 8; i++)
#pragma unroll
        for (int c = 0; c < 8; c++) acc[i][c] = 0.f;

    if (dt) {
        for (int k = 0; k < 100; k += 4) {
            float a[8][4];
#pragma unroll
            for (int i = 0; i < 8; i++) {
                f32x4 f = ntld4((const float*)Xin_ + (r0 + i) * 100 + k);
                a[i][0] = f.x; a[i][1] = f.y; a[i][2] = f.z; a[i][3] = f.w;
            }
            mm_inner(a, wlds, k, c0, acc);
        }
    } else {
        for (int k = 0; k < 100; k += 4) {
            float a[8][4];
#pragma unroll
            for (int i = 0; i < 8; i++) {
                u16x4 u = ntld4u((const unsigned short*)Xin_ + (r0 + i) * 100 + k);
                a[i][0] = us2f(u.x); a[i][1] = us2f(u.y);
                a[i][2] = us2f(u.z); a[i][3] = us2f(u.w);
            }
            mm_inner(a, wlds, k, c0, acc);
        }
    }
#pragma unroll
    for (int i = 0; i < 8; i++) {
        float4 o0 = {acc[i][0], acc[i][1], acc[i][2], acc[i][3]};
        float4 o1 = {acc[i][4], acc[i][5], acc[i][6], acc[i][7]};
        *(float4*)&H[(r0 + i) * 128 + c0] = o0;
        *(float4*)&H[(r0 + i) * 128 + c0 + 64] = o1;
    }
}

// --------- layers 2/3 GEMM: H = Xws @ W (128 x 128), fp32 ws input ---------
__global__ __launch_bounds__(256, 2) void k_mm(const float* __restrict__ Xin,
                                               const void* __restrict__ W,
                                               const int* __restrict__ flag,
                                               float* __restrict__ H) {
    __shared__ float wlds[128 * 128];
    const int dt = *flag;
    const int tid = threadIdx.x;
    if (dt) {
        const float* Wf = (const float*)W;
        for (int idx = tid; idx < 128 * 128; idx += 256) wlds[idx] = Wf[idx];
    } else {
        const unsigned short* Wb = (const unsigned short*)W;
        for (int idx = tid; idx < 128 * 128; idx += 256) wlds[idx] = us2f(Wb[idx]);
    }
    __syncthreads();
    const int tx = tid & 15, ty = tid >> 4;
    const int c0 = tx * 4;
    const size_t r0 = (size_t)blockIdx.x * 128 + (size_t)ty * 8;
    float acc[8][8];
#pragma unroll
    for (int i = 0; i < 8; i++)
#pragma unroll
        for (int c = 0; c < 8; c++) acc[i][c] = 0.f;

    for (int k = 0; k < 128; k += 4) {
        float a[8][4];
#pragma unroll
        for (int i = 0; i < 8; i++) {
            f32x4 f = ntld4(&Xin[(r0 + i) * 128 + k]);
            a[i][0] = f.x; a[i][1] = f.y; a[i][2] = f.z; a[i][3] = f.w;
        }
        mm_inner(a, wlds, k, c0, acc);
    }
#pragma unroll
    for (int i = 0; i < 8; i++) {
        float4 o0 = {acc[i][0], acc[i][1], acc[i][2], acc[i][3]};
        float4 o1 = {acc[i][4], acc[i][5], acc[i][6], acc[i][7]};
        *(float4*)&H[(r0 + i) * 128 + c0] = o0;
        *(float4*)&H[(r0 + i) * 128 + c0 + 64] = o1;
    }
}

// ------------- aggregate + self + bias + tanh (Dout=128), 4-way MLP -------------
__global__ __launch_bounds__(256) void k_agg(const float* __restrict__ H,
                                             const float* __restrict__ dis,
                                             const int* __restrict__ rowptr,
                                             const int* __restrict__ col,
                                             const void* __restrict__ bias,
                                             const int* __restrict__ flag,
                                             float* __restrict__ Xout) {
    const int dt = *flag;
    const int lane = threadIdx.x & 31;
    const int node = blockIdx.x * 8 + (threadIdx.x >> 5);
    if (node >= NN) return;
    const int c0 = lane * 4;
    const size_t base = (size_t)node * 128 + c0;
    float4 h = *(const float4*)&H[base];
    float sn = dis[node], s2 = sn * sn;
    float4 acc;
    acc.x = fmaf(h.x, s2, ldf(bias, c0 + 0, dt));
    acc.y = fmaf(h.y, s2, ldf(bias, c0 + 1, dt));
    acc.z = fmaf(h.z, s2, ldf(bias, c0 + 2, dt));
    acc.w = fmaf(h.w, s2, ldf(bias, c0 + 3, dt));
    int e = rowptr[node], e1 = rowptr[node + 1];
    for (; e + 4 <= e1; e += 4) {
        int n0 = col[e], n1 = col[e + 1], n2 = col[e + 2], n3 = col[e + 3];
        float w0 = dis[n0] * sn, w1 = dis[n1] * sn, w2 = dis[n2] * sn, w3 = dis[n3] * sn;
        float4 h0 = *(const float4*)&H[(size_t)n0 * 128 + c0];
        float4 h1 = *(const float4*)&H[(size_t)n1 * 128 + c0];
        float4 h2 = *(const float4*)&H[(size_t)n2 * 128 + c0];
        float4 h3 = *(const float4*)&H[(size_t)n3 * 128 + c0];
        acc.x = fmaf(h0.x, w0, acc.x); acc.y = fmaf(h0.y, w0, acc.y);
        acc.z = fmaf(h0.z, w0, acc.z); acc.w = fmaf(h0.w, w0, acc.w);
        acc.x = fmaf(h1.x, w1, acc.x); acc.y = fmaf(h1.y, w1, acc.y);
        acc.z = fmaf(h1.z, w1, acc.z); acc.w = fmaf(h1.w, w1, acc.w);
        acc.x = fmaf(h2.x, w2, acc.x); acc.y = fmaf(h2.y, w2, acc.y);
        acc.z = fmaf(h2.z, w2, acc.z); acc.w = fmaf(h2.w, w2, acc.w);
        acc.x = fmaf(h3.x, w3, acc.x); acc.y = fmaf(h3.y, w3, acc.y);
        acc.z = fmaf(h3.z, w3, acc.z); acc.w = fmaf(h3.w, w3, acc.w);
    }
    for (; e < e1; ++e) {
        int nb = col[e];
        float w = dis[nb] * sn;
        float4 hn = *(const float4*)&H[(size_t)nb * 128 + c0];
        acc.x = fmaf(hn.x, w, acc.x); acc.y = fmaf(hn.y, w, acc.y);
        acc.z = fmaf(hn.z, w, acc.z); acc.w = fmaf(hn.w, w, acc.w);
    }
    f32x4 o = {tanhf(acc.x), tanhf(acc.y), tanhf(acc.z), tanhf(acc.w)};
    ntst4(&Xout[base], o);
}

// ------- fused layer-3 agg + tanh + dot W4, 4-way MLP -------
__global__ __launch_bounds__(256) void k_h4(const float* __restrict__ H3,
                                            const float* __restrict__ dis,
                                            const int* __restrict__ rowptr,
                                            const int* __restrict__ col,
                                            const void* __restrict__ b3,
                                            const void* __restrict__ W4,
                                            const int* __restrict__ flag,
                                            float* __restrict__ h4) {
    const int dt = *flag;
    const int lane = threadIdx.x & 31;
    const int node = blockIdx.x * 8 + (threadIdx.x >> 5);
    if (node >= NN) return;
    const int c0 = lane * 4;
    const size_t base = (size_t)node * 128 + c0;
    float4 h = *(const float4*)&H3[base];
    float sn = dis[node], s2 = sn * sn;
    float4 acc;
    acc.x = fmaf(h.x, s2, ldf(b3, c0 + 0, dt));
    acc.y = fmaf(h.y, s2, ldf(b3, c0 + 1, dt));
    acc.z = fmaf(h.z, s2, ldf(b3, c0 + 2, dt));
    acc.w = fmaf(h.w, s2, ldf(b3, c0 + 3, dt));
    int e = rowptr[node], e1 = rowptr[node + 1];
    for (; e + 4 <= e1; e += 4) {
        int n0 = col[e], n1 = col[e + 1], n2 = col[e + 2], n3 = col[e + 3];
        float w0 = dis[n0] * sn, w1 = dis[n1] * sn, w2 = dis[n2] * sn, w3 = dis[n3] * sn;
        float4 h0 = *(const float4*)&H3[(size_t)n0 * 128 + c0];
        float4 h1 = *(const float4*)&H3[(size_t)n1 * 128 + c0];
        float4 h2 = *(const float4*)&H3[(size_t)n2 * 128 + c0];
        float4 h3 = *(const float4*)&H3[(size_t)n3 * 128 + c0];
        acc.x = fmaf(h0.x, w0, acc.x); acc.y = fmaf(h0.y, w0, acc.y);
        acc.z = fmaf(h0.z, w0, acc.z); acc.w = fmaf(h0.w, w0, acc.w);
        acc.x = fmaf(h1.x, w1, acc.x); acc.y = fmaf(h1.y, w1, acc.y);
        acc.z = fmaf(h1.z, w1, acc.z); acc.w = fmaf(h1.w, w1, acc.w);
        acc.x = fmaf(h2.x, w2, acc.x); acc.y = fmaf(h2.y, w2, acc.y);
        acc.z = fmaf(h2.z, w2, acc.z); acc.w = fmaf(h2.w, w2, acc.w);
        acc.x = fmaf(h3.x, w3, acc.x); acc.y = fmaf(h3.y, w3, acc.y);
        acc.z = fmaf(h3.z, w3, acc.z); acc.w = fmaf(h3.w, w3, acc.w);
    }
    for (; e < e1; ++e) {
        int nb = col[e];
        float w = dis[nb] * sn;
        float4 hn = *(const float4*)&H3[(size_t)nb * 128 + c0];
        acc.x = fmaf(hn.x, w, acc.x); acc.y = fmaf(hn.y, w, acc.y);
        acc.z = fmaf(hn.z, w, acc.z); acc.w = fmaf(hn.w, w, acc.w);
    }
    float v = tanhf(acc.x) * ldf(W4, c0 + 0, dt) + tanhf(acc.y) * ldf(W4, c0 + 1, dt) +
              tanhf(acc.z) * ldf(W4, c0 + 2, dt) + tanhf(acc.w) * ldf(W4, c0 + 3, dt);
#pragma unroll
    for (int off = 16; off > 0; off >>= 1) v += __shfl_xor(v, off, 64);
    if (lane == 0) h4[node] = v;
}

__global__ void k_agg4(const float* __restrict__ h4, const float* __restrict__ dis,
                       const int* __restrict__ rowptr, const int* __restrict__ col,
                       const void* __restrict__ b4, const int* __restrict__ flag,
                       float* __restrict__ score) {
    const int dt = *flag;
    int i = blockIdx.x * 256 + threadIdx.x;
    if (i >= NN) return;
    float sn = dis[i];
    float acc = fmaf(h4[i] * sn, sn, ldf(b4, 0, dt));
    int e = rowptr[i], e1 = rowptr[i + 1];
    for (; e + 4 <= e1; e += 4) {
        int n0 = col[e], n1 = col[e + 1], n2 = col[e + 2], n3 = col[e + 3];
        float v0 = h4[n0] * dis[n0], v1 = h4[n1] * dis[n1];
        float v2 = h4[n2] * dis[n2], v3 = h4[n3] * dis[n3];
        acc = fmaf(v0 + v1 + v2 + v3, sn, acc);
    }
    for (; e < e1; ++e) {
        int nb = col[e];
        acc = fmaf(h4[nb] * dis[nb], sn, acc);
    }
    score[i] = tanhf(acc);
}

// ------------- radix-histogram top-64 per graph -------------
__global__ void k_hist(const float* __restrict__ score, const int* __restrict__ batch,
                       int* __restrict__ hist) {
    int i = blockIdx.x * 256 + threadIdx.x;
    if (i >= NN) return;
    unsigned u = fkey(score[i]);
    atomicAdd(&hist[batch[i] * 2048 + (u >> 21)], 1);
}

__global__ void k_thr(const int* __restrict__ hist, int* __restrict__ thr) {
    int g = threadIdx.x;
    if (g < GG) {
        int cum = 0, b = 0;
        for (int bin = 2047; bin >= 0; --bin) {
            cum += hist[g * 2048 + bin];
            if (cum >= 64) { b = bin; break; }
        }
        thr[g] = b;
    }
}

__global__ void k_collect(const float* __restrict__ score, const int* __restrict__ batch,
                          const int* __restrict__ thr, int* __restrict__ ccnt,
                          unsigned long long* __restrict__ cbuf) {
    int i = blockIdx.x * 256 + threadIdx.x;
    if (i >= NN) return;
    int g = batch[i];
    unsigned u = fkey(score[i]);
    if ((int)(u >> 21) >= thr[g]) {
        int p = atomicAdd(&ccnt[g], 1);
        if (p < CCAP)
            cbuf[(size_t)g * CCAP + p] =
                ((unsigned long long)u << 32) | (unsigned)(~(unsigned)i);
    }
}

__global__ __launch_bounds__(64) void k_top64(const unsigned long long* __restrict__ cbuf,
                                              const int* __restrict__ ccnt,
                                              int* __restrict__ sel) {
    __shared__ unsigned long long lds[4096];
    int g = blockIdx.x, t = threadIdx.x;
    int C = ccnt[g];
    if (C > CCAP) C = CCAP;
    const unsigned long long* src = cbuf + (size_t)g * CCAP;
    int CL = C < 4096 ? C : 4096;
    for (int i = t; i < CL; i += 64) lds[i] = src[i];
    __syncthreads();
    unsigned long long prev = ~0ULL;
    for (int k = 0; k < 64; ++k) {
        unsigned long long best = 0;
        for (int i = t; i < CL; i += 64) {
            unsigned long long v = lds[i];
            if (v < prev && v > best) best = v;
        }
        for (int i = 4096 + t; i < C; i += 64) {
            unsigned long long v = src[i];
            if (v < prev && v > best) best = v;
        }
#pragma unroll
        for (int off = 32; off > 0; off >>= 1) {
            unsigned long long o = __shfl_xor(best, off, 64);
            if (o > best) best = o;
        }
        if (t == 0)
            sel[g * 64 + k] = (best == 0) ? -1 : (int)~(unsigned)(best & 0xffffffffu);
        prev = best;
    }
}

// ------- recompute X1 rows for selected nodes (from x, W1, CSR) -------
__global__ __launch_bounds__(128) void k_x1sel(const void* __restrict__ x,
                                               const void* __restrict__ W1,
                                               const void* __restrict__ b1,
                                               const float* __restrict__ dis,
                                               const int* __restrict__ rowptr,
                                               const int* __restrict__ col,
                                               const int* __restrict__ sel,
                                               const int* __restrict__ flag,
                                               float* __restrict__ X1sel) {
    __shared__ float wl[100 * 128];
    __shared__ float xr[104];
    const int dt = *flag;
    int p = blockIdx.x, t = threadIdx.x;
    if (dt) {
        const float* Wf = (const float*)W1;
        for (int idx = t; idx < 100 * 128; idx += 128) wl[idx] = Wf[idx];
    } else {
        const unsigned short* Wb = (const unsigned short*)W1;
        for (int idx = t; idx < 100 * 128; idx += 128) wl[idx] = us2f(Wb[idx]);
    }
    int si = sel[p];
    __syncthreads();
    if (si < 0) { X1sel[p * 128 + t] = 0.f; return; }
    float sn = dis[si], s2 = sn * sn;
    for (int idx = t; idx < 100; idx += 128) xr[idx] = ldf(x, (long)si * 100 + idx, dt);
    __syncthreads();
    float h = 0.f;
    for (int k = 0; k < 100; ++k) h = fmaf(xr[k], wl[k * 128 + t], h);
    float acc = fmaf(h, s2, ldf(b1, t, dt));
    int e0 = rowptr[si], e1 = rowptr[si + 1];
    for (int e = e0; e < e1; ++e) {
        int nb = col[e];
        __syncthreads();
        for (int idx = t; idx < 100; idx += 128) xr[idx] = ldf(x, (long)nb * 100 + idx, dt);
        __syncthreads();
        h = 0.f;
        for (int k = 0; k < 100; ++k) h = fmaf(xr[k], wl[k * 128 + t], h);
        acc = fmaf(h, dis[nb] * sn, acc);
    }
    X1sel[p * 128 + t] = tanhf(acc);
}

// ------- recompute X3 rows for selected nodes (from H3, CSR) -------
__global__ __launch_bounds__(128) void k_x3sel(const float* __restrict__ H3,
                                               const void* __restrict__ b3,
                                               const float* __restrict__ dis,
                                               const int* __restrict__ rowptr,
                                               const int* __restrict__ col,
                                               const int* __restrict__ sel,
                                               const int* __restrict__ flag,
                                               float* __restrict__ X3sel) {
    const int dt = *flag;
    int p = blockIdx.x, t = threadIdx.x;
    int si = sel[p];
    if (si < 0) { X3sel[p * 128 + t] = 0.f; return; }
    float sn = dis[si], s2 = sn * sn;
    float acc = fmaf(H3[(size_t)si * 128 + t], s2, ldf(b3, t, dt));
    int e1 = rowptr[si + 1];
    for (int e = rowptr[si]; e < e1; ++e) {
        int nb = col[e];
        acc = fmaf(H3[(size_t)nb * 128 + t], dis[nb] * sn, acc);
    }
    X3sel[p * 128 + t] = tanhf(acc);
}

// -------- gather pooled row + conv5 (kernel=stride=385) + relu --------
__global__ __launch_bounds__(64) void k_gconv5(const int* __restrict__ sel,
                                               const float* __restrict__ X1sel,
                                               const float* __restrict__ X2,
                                               const float* __restrict__ X3sel,
                                               const float* __restrict__ score,
                                               const void* __restrict__ cw5,
                                               const void* __restrict__ cb5,
                                               const int* __restrict__ flag,
                                               float* __restrict__ h5) {
    __shared__ float feat[DCAT];
    const int dt = *flag;
    int g = blockIdx.x >> 6, t = blockIdx.x & 63;
    int p = g * 64 + t;
    int si = sel[p];
    for (int d = threadIdx.x; d < DCAT; d += 64) {
        float v = 0.f;
        if (si >= 0) {
            if (d < 128) v = X1sel[p * 128 + d];
            else if (d < 256) v = X2[(size_t)si * 128 + d - 128];
            else if (d < 384) v = X3sel[p * 128 + d - 256];
            else v = score[si];
        }
        feat[d] = v;
    }
    __syncthreads();
    int oc = threadIdx.x;
    float acc = ldf(cb5, oc, dt);
    if (dt) {
        const float* w = (const float*)cw5 + (size_t)oc * DCAT;
        for (int d = 0; d < DCAT; ++d) acc = fmaf(feat[d], w[d], acc);
    } else {
        const unsigned short* w = (const unsigned short*)cw5 + (size_t)oc * DCAT;
        for (int d = 0; d < DCAT; ++d) acc = fmaf(feat[d], us2f(w[d]), acc);
    }
    h5[(g * 64 + oc) * 64 + t] = fmaxf(acc, 0.f);
}

// -------- maxpool(2) + conv6 (64ch -> 128ch, k=5) + relu -> emb --------
__global__ __launch_bounds__(128) void k_conv6(const float* __restrict__ h5,
                                               const void* __restrict__ cw6,
                                               const void* __restrict__ cb6,
                                               const int* __restrict__ flag,
                                               float* __restrict__ emb) {
    __shared__ float hp[64][32];
    const int dt = *flag;
    int g = blockIdx.x;
    for (int idx = threadIdx.x; idx < 2048; idx += 128) {
        int ic = idx >> 5, u = idx & 31;
        float a = h5[g * 4096 + ic * 64 + 2 * u];
        float b = h5[g * 4096 + ic * 64 + 2 * u + 1];
        hp[ic][u] = fmaxf(a, b);
    }
    __syncthreads();
    int oc = threadIdx.x;
    float acc[28];
#pragma unroll
    for (int p = 0; p < 28; ++p) acc[p] = 0.f;
    for (int ic = 0; ic < 64; ++ic) {
        float w[5];
#pragma unroll
        for (int k = 0; k < 5; ++k) w[k] = ldf(cw6, (long)oc * 320 + ic * 5 + k, dt);
        float hv[32];
#pragma unroll
        for (int u = 0; u < 32; ++u) hv[u] = hp[ic][u];
#pragma unroll
        for (int p = 0; p < 28; ++p)
#pragma unroll
            for (int k = 0; k < 5; ++k) acc[p] = fmaf(hv[p + k], w[k], acc[p]);
    }
    float cb = ldf(cb6, oc, dt);
    for (int p = 0; p < 28; ++p)
        emb[g * 3584 + oc * 28 + p] = fmaxf(acc[p] + cb, 0.f);
}

// ---------------- FC layers ----------------
__global__ __launch_bounds__(256) void k_fc1(const float* __restrict__ emb,
                                             const void* __restrict__ fw1,
                                             const void* __restrict__ fb1,
                                             const int* __restrict__ flag,
                                             float* __restrict__ out128) {
    __shared__ float red[256];
    const int dt = *flag;
    int j = blockIdx.x;
    float acc = 0.f;
    if (dt) {
        const float* w = (const float*)fw1 + (size_t)j * 39424;
        for (int i = threadIdx.x; i < 39424; i += 256) acc = fmaf(emb[i], w[i], acc);
    } else {
        const unsigned short* w = (const unsigned short*)fw1 + (size_t)j * 39424;
        for (int i = threadIdx.x; i < 39424; i += 256) acc = fmaf(emb[i], us2f(w[i]), acc);
    }
    red[threadIdx.x] = acc;
    __syncthreads();
    for (int s = 128; s > 0; s >>= 1) {
        if (threadIdx.x < s) red[threadIdx.x] += red[threadIdx.x + s];
        __syncthreads();
    }
    if (threadIdx.x == 0) out128[j] = fmaxf(red[0] + ldf(fb1, j, dt), 0.f);
}

__global__ void k_fc2(const float* __restrict__ out128,
                      const void* __restrict__ fw2,
                      const void* __restrict__ fb2,
                      const int* __restrict__ flag,
                      void* __restrict__ outv) {
    const int dt = *flag;
    int c = threadIdx.x;
    if (c < 10) {
        float acc = ldf(fb2, c, dt);
        for (int j = 0; j < 128; ++j) acc = fmaf(out128[j], ldf(fw2, c * 128 + j, dt), acc);
        if (dt) ((float*)outv)[c] = acc;
        else ((__hip_bfloat16*)outv)[c] = __float2bfloat16(acc);
    }
}

extern "C" void kernel_launch(void* const* d_in, const int* in_sizes, int n_in,
                              void* d_out, int out_size, void* d_ws, size_t ws_size,
                              hipStream_t stream) {
    const void* x = d_in[0];
    const int* ei = (const int*)d_in[1];
    const int* batch = (const int*)d_in[2];
    const void* W1 = d_in[3];
    const void* b1 = d_in[4];
    const void* W2 = d_in[5];
    const void* b2 = d_in[6];
    const void* W3 = d_in[7];
    const void* b3 = d_in[8];
    const void* W4 = d_in[9];
    const void* b4 = d_in[10];
    const void* cw5 = d_in[11];
    const void* cb5 = d_in[12];
    const void* cw6 = d_in[13];
    const void* cb6 = d_in[14];
    const void* fw1 = d_in[15];
    const void* fb1 = d_in[16];
    const void* fw2 = d_in[17];
    const void* fb2 = d_in[18];

    // ---- workspace layout: H buffers 512B-aligned (gather rows = 4 cache lines) ----
    const size_t BIG = (size_t)NN * 128;
    float* f_A = (float*)(((size_t)d_ws + 511) & ~(size_t)511); // BIG (H1->H2->H3)
    float* f_B = f_A + BIG;                      // BIG  (X1 -> X2)  (BIG*4 % 512 == 0)
    float* f_dis = f_B + BIG;                    // NN
    float* f_score = f_dis + NN;                 // NN
    float* f_h4 = f_score + NN;                  // NN
    float* f_h5 = f_h4 + NN;                     // 45056
    float* f_emb = f_h5 + 45056;                 // 39424
    float* f_o128 = f_emb + 39424;               // 128
    float* f_X1sel = f_o128 + 128;               // 704*128
    float* f_X3sel = f_X1sel + 704 * 128;        // 704*128
    int* i_degcnt = (int*)(f_X3sel + 704 * 128); // NN   (zeroed region start)
    int* i_fill = i_degcnt + NN;                 // NN
    int* i_hist = i_fill + NN;                   // GG*2048
    int* i_ccnt = i_hist + GG * 2048;            // 16
    int* i_rowptr = i_ccnt + 16;                 // NN+1
    int* i_col = i_rowptr + NN + 1;              // EE
    int* i_bsum = i_col + EE;                    // 512
    int* i_thr = i_bsum + 512;                   // 16
    int* i_sel = i_thr + 16;                     // 704
    unsigned long long* c_buf =
        (unsigned long long*)(((size_t)(i_sel + 704) + 15) & ~(size_t)15); // GG*CCAP
    int* i_flag = (int*)(c_buf + (size_t)GG * CCAP); // 4 ints (dedicated, never clobbered)
    size_t need_bytes = (size_t)((char*)(i_flag + 4) - (char*)d_ws);

    if (ws_size < need_bytes) return; // harness pre-zeroes d_out -> clean absmax fail

    k_detect<<<1, 64, 0, stream>>>((const unsigned int*)x, i_flag);

    const int EB = (EE + 255) / 256;
    const int NB = (NN + 255) / 256;
    const int SB = (NN + 1023) / 1024;

    hipMemsetAsync(i_degcnt, 0, sizeof(int) * (2 * NN + GG * 2048 + 16), stream);

    k_deg<<<EB, 256, 0, stream>>>(ei, i_degcnt);
    k_dis<<<NB, 256, 0, stream>>>(i_degcnt, f_dis);
    k_scan1<<<SB, 256, 0, stream>>>(i_degcnt, i_rowptr + 1, i_bsum, NN);
    k_scan2<<<1, 512, 0, stream>>>(i_bsum, SB);
    k_scan3<<<NB, 256, 0, stream>>>(i_rowptr, i_bsum, NN);
    k_fill<<<EB, 256, 0, stream>>>(ei, i_rowptr, i_fill, i_col);

    const int MMB = NN / 128;  // 3125 (exact)
    const int AGB = NN / 8;    // 50000

    k_mm1<<<MMB, 256, 0, stream>>>(x, W1, i_flag, f_A);
    k_agg<<<AGB, 256, 0, stream>>>(f_A, f_dis, i_rowptr, i_col, b1, i_flag, f_B);
    k_mm<<<MMB, 256, 0, stream>>>(f_B, W2, i_flag, f_A);
    k_agg<<<AGB, 256, 0, stream>>>(f_A, f_dis, i_rowptr, i_col, b2, i_flag, f_B);
    k_mm<<<MMB, 256, 0, stream>>>(f_B, W3, i_flag, f_A);
    k_h4<<<AGB, 256, 0, stream>>>(f_A, f_dis, i_rowptr, i_col, b3, W4, i_flag, f_h4);
    k_agg4<<<NB, 256, 0, stream>>>(f_h4, f_dis, i_rowptr, i_col, b4, i_flag, f_score);

    k_hist<<<NB, 256, 0, stream>>>(f_score, batch, i_hist);
    k_thr<<<1, 64, 0, stream>>>(i_hist, i_thr);
    k_collect<<<NB, 256, 0, stream>>>(f_score, batch, i_thr, i_ccnt, c_buf);
    k_top64<<<GG, 64, 0, stream>>>(c_buf, i_ccnt, i_sel);

    k_x1sel<<<GG * 64, 128, 0, stream>>>(x, W1, b1, f_dis, i_rowptr, i_col, i_sel, i_flag, f_X1sel);
    k_x3sel<<<GG * 64, 128, 0, stream>>>(f_A, b3, f_dis, i_rowptr, i_col, i_sel, i_flag, f_X3sel);

    k_gconv5<<<GG * 64, 64, 0, stream>>>(i_sel, f_X1sel, f_B, f_X3sel, f_score, cw5, cb5, i_flag, f_h5);
    k_conv6<<<GG, 128, 0, stream>>>(f_h5, cw6, cb6, i_flag, f_emb);
    k_fc1<<<128, 256, 0, stream>>>(f_emb, fw1, fb1, i_flag, f_o128);
    k_fc2<<<1, 128, 0, stream>>>(f_o128, fw2, fb2, i_flag, d_out);

    (void)in_sizes; (void)n_in; (void)ws_size;
}

// Round 7
// 1821.324 us; speedup vs baseline: 1.0961x; 1.0961x over previous
//
#include <hip/hip_runtime.h>
#include <hip/hip_bf16.h>

// GASTLCModel: 4-layer GCN (tanh) -> SortPool top-64/graph -> conv5(k=385,s=385)
// -> maxpool2 -> conv6(k=5) -> FC(39424->128) -> FC(128->10).
// Float dtype (fp32 vs bf16) detected at runtime; all compute fp32.
// R7: keep 512B-aligned H + NT store of X (protect L3 residency of the 4x-reused
// gather target H; X is read exactly once downstream). REVERT NT loads in GEMMs
// (R6 showed they break intra-kernel line reuse: FETCH 205->477 MB, +100us).

#define NN 400000
#define EE 1600000
#define GG 11
#define DCAT 385
#define CCAP 40960

typedef float f32x4 __attribute__((ext_vector_type(4)));

__device__ __forceinline__ float us2f(unsigned short u) {
    return __uint_as_float(((unsigned)u) << 16);
}
__device__ __forceinline__ float ldf(const void* p, long i, int dt) {
    return dt ? ((const float*)p)[i] : us2f(((const unsigned short*)p)[i]);
}
__device__ __forceinline__ unsigned fkey(float s) {
    unsigned u = __float_as_uint(s);
    return (u & 0x80000000u) ? ~u : (u | 0x80000000u);
}
__device__ __forceinline__ void ntst4(float* p, f32x4 v) {
    __builtin_nontemporal_store(v, (f32x4*)p);
}

// ---------------- dtype detect: dt=1 fp32, dt=0 bf16 ----------------
__global__ void k_detect(const unsigned int* __restrict__ xw, int* __restrict__ flag) {
    if (threadIdx.x == 0) {
        int good = 0;
        for (int i = 0; i < 64; ++i) {
            float a = fabsf(us2f((unsigned short)(xw[i] & 0xffffu)));
            if (a > 0.004f && a < 16.f) ++good;
        }
        *flag = (good >= 32) ? 0 : 1;
    }
}

// ---------------- CSR build ----------------
__global__ void k_deg(const int* __restrict__ ei, int* __restrict__ degcnt) {
    int e = blockIdx.x * 256 + threadIdx.x;
    if (e >= EE) return;
    int s = ei[e], d = ei[EE + e];
    if (s != d) atomicAdd(&degcnt[d], 1);
}

__global__ void k_dis(const int* __restrict__ degcnt, float* __restrict__ dis) {
    int i = blockIdx.x * 256 + threadIdx.x;
    if (i < NN) dis[i] = 1.0f / sqrtf((float)degcnt[i] + 1.0f);
}

__global__ __launch_bounds__(256) void k_scan1(const int* __restrict__ in,
                                               int* __restrict__ out1,
                                               int* __restrict__ bsums, int n) {
    __shared__ int lds[256];
    int tid = threadIdx.x;
    int base = blockIdx.x * 1024 + tid * 4;
    int v0 = (base + 0 < n) ? in[base + 0] : 0;
    int v1 = (base + 1 < n) ? in[base + 1] : 0;
    int v2 = (base + 2 < n) ? in[base + 2] : 0;
    int v3 = (base + 3 < n) ? in[base + 3] : 0;
    v1 += v0; v2 += v1; v3 += v2;
    lds[tid] = v3;
    __syncthreads();
    for (int off = 1; off < 256; off <<= 1) {
        int x = (tid >= off) ? lds[tid - off] : 0;
        __syncthreads();
        lds[tid] += x;
        __syncthreads();
    }
    int prefix = (tid > 0) ? lds[tid - 1] : 0;
    if (base + 0 < n) out1[base + 0] = prefix + v0;
    if (base + 1 < n) out1[base + 1] = prefix + v1;
    if (base + 2 < n) out1[base + 2] = prefix + v2;
    if (base + 3 < n) out1[base + 3] = prefix + v3;
    if (tid == 255) bsums[blockIdx.x] = lds[255];
}

__global__ __launch_bounds__(512) void k_scan2(int* __restrict__ bsums, int nb) {
    __shared__ int lds[512];
    int tid = threadIdx.x;
    lds[tid] = (tid < nb) ? bsums[tid] : 0;
    __syncthreads();
    for (int off = 1; off < 512; off <<= 1) {
        int x = (tid >= off) ? lds[tid - off] : 0;
        __syncthreads();
        lds[tid] += x;
        __syncthreads();
    }
    int ex = (tid > 0) ? lds[tid - 1] : 0;
    if (tid < nb) bsums[tid] = ex;
}

__global__ void k_scan3(int* __restrict__ rowptr, const int* __restrict__ bsums, int n) {
    int i = blockIdx.x * 256 + threadIdx.x;
    if (i < n) rowptr[i + 1] += bsums[i >> 10];
    if (i == 0) rowptr[0] = 0;
}

__global__ void k_fill(const int* __restrict__ ei, const int* __restrict__ rowptr,
                       int* __restrict__ fill, int* __restrict__ col) {
    int e = blockIdx.x * 256 + threadIdx.x;
    if (e >= EE) return;
    int s = ei[e], d = ei[EE + e];
    if (s != d) {
        int p = atomicAdd(&fill[d], 1);
        col[rowptr[d] + p] = s;
    }
}

// ---- shared GEMM inner: acc[8][8] += a[8][4] (x) wlds[(k+j)*128 + c0/(+64)] ----
__device__ __forceinline__ void mm_inner(const float (&a)[8][4],
                                         const float* __restrict__ wlds, int k,
                                         int c0, float (&acc)[8][8]) {
#pragma unroll
    for (int j = 0; j < 4; j++) {
        float4 b0 = *(const float4*)&wlds[(k + j) * 128 + c0];
        float4 b1 = *(const float4*)&wlds[(k + j) * 128 + c0 + 64];
#pragma unroll
        for (int i = 0; i < 8; i++) {
            float av = a[i][j];
            acc[i][0] = fmaf(av, b0.x, acc[i][0]);
            acc[i][1] = fmaf(av, b0.y, acc[i][1]);
            acc[i][2] = fmaf(av, b0.z, acc[i][2]);
            acc[i][3] = fmaf(av, b0.w, acc[i][3]);
            acc[i][4] = fmaf(av, b1.x, acc[i][4]);
            acc[i][5] = fmaf(av, b1.y, acc[i][5]);
            acc[i][6] = fmaf(av, b1.z, acc[i][6]);
            acc[i][7] = fmaf(av, b1.w, acc[i][7]);
        }
    }
}

// --------- layer-1 GEMM: H = x @ W1 (100 x 128), dtype-adaptive ---------
__global__ __launch_bounds__(256, 2) void k_mm1(const void* __restrict__ Xin_,
                                                const void* __restrict__ W,
                                                const int* __restrict__ flag,
                                                float* __restrict__ H) {
    __shared__ float wlds[100 * 128];
    const int dt = *flag;
    const int tid = threadIdx.x;
    if (dt) {
        const float* Wf = (const float*)W;
        for (int idx = tid; idx < 100 * 128; idx += 256) wlds[idx] = Wf[idx];
    } else {
        const unsigned short* Wb = (const unsigned short*)W;
        for (int idx = tid; idx < 100 * 128; idx += 256) wlds[idx] = us2f(Wb[idx]);
    }
    __syncthreads();
    const int tx = tid & 15, ty = tid >> 4;
    const int c0 = tx * 4;
    const size_t r0 = (size_t)blockIdx.x * 128 + (size_t)ty * 8;
    float acc[8][8];
#pragma unroll
    for (int i = 0; i < 8; i++)
#pragma unroll
        for (int c = 0; c < 8; c++) acc[i][c] = 0.f;

    if (dt) {
        for (int k = 0; k < 100; k += 4) {
            float a[8][4];
#pragma unroll
            for (int i = 0; i < 8; i++) {
                float4 f = *(const float4*)((const float*)Xin_ + (r0 + i) * 100 + k);
                a[i][0] = f.x; a[i][1] = f.y; a[i][2] = f.z; a[i][3] = f.w;
            }
            mm_inner(a, wlds, k, c0, acc);
        }
    } else {
        for (int k = 0; k < 100; k += 4) {
            float a[8][4];
#pragma unroll
            for (int i = 0; i < 8; i++) {
                ushort4 u = *(const ushort4*)((const unsigned short*)Xin_ + (r0 + i) * 100 + k);
                a[i][0] = us2f(u.x); a[i][1] = us2f(u.y);
                a[i][2] = us2f(u.z); a[i][3] = us2f(u.w);
            }
            mm_inner(a, wlds, k, c0, acc);
        }
    }
#pragma unroll
    for (int i = 0; i < 8; i++) {
        float4 o0 = {acc[i][0], acc[i][1], acc[i][2], acc[i][3]};
        float4 o1 = {acc[i][4], acc[i][5], acc[i][6], acc[i][7]};
        *(float4*)&H[(r0 + i) * 128 + c0] = o0;
        *(float4*)&H[(r0 + i) * 128 + c0 + 64] = o1;
    }
}

// --------- layers 2/3 GEMM: H = Xws @ W (128 x 128), fp32 ws input ---------
__global__ __launch_bounds__(256, 2) void k_mm(const float* __restrict__ Xin,
                                               const void* __restrict__ W,
                                               const int* __restrict__ flag,
                                               float* __restrict__ H) {
    __shared__ float wlds[128 * 128];
    const int dt = *flag;
    const int tid = threadIdx.x;
    if (dt) {
        const float* Wf = (const float*)W;
        for (int idx = tid; idx < 128 * 128; idx += 256) wlds[idx] = Wf[idx];
    } else {
        const unsigned short* Wb = (const unsigned short*)W;
        for (int idx = tid; idx < 128 * 128; idx += 256) wlds[idx] = us2f(Wb[idx]);
    }
    __syncthreads();
    const int tx = tid & 15, ty = tid >> 4;
    const int c0 = tx * 4;
    const size_t r0 = (size_t)blockIdx.x * 128 + (size_t)ty * 8;
    float acc[8][8];
#pragma unroll
    for (int i = 0; i < 8; i++)
#pragma unroll
        for (int c = 0; c < 8; c++) acc[i][c] = 0.f;

    for (int k = 0; k < 128; k += 4) {
        float a[8][4];
#pragma unroll
        for (int i = 0; i < 8; i++) {
            float4 f = *(const float4*)&Xin[(r0 + i) * 128 + k];
            a[i][0] = f.x; a[i][1] = f.y; a[i][2] = f.z; a[i][3] = f.w;
        }
        mm_inner(a, wlds, k, c0, acc);
    }
#pragma unroll
    for (int i = 0; i < 8; i++) {
        float4 o0 = {acc[i][0], acc[i][1], acc[i][2], acc[i][3]};
        float4 o1 = {acc[i][4], acc[i][5], acc[i][6], acc[i][7]};
        *(float4*)&H[(r0 + i) * 128 + c0] = o0;
        *(float4*)&H[(r0 + i) * 128 + c0 + 64] = o1;
    }
}

// ------------- aggregate + self + bias + tanh (Dout=128), 4-way MLP -------------
__global__ __launch_bounds__(256) void k_agg(const float* __restrict__ H,
                                             const float* __restrict__ dis,
                                             const int* __restrict__ rowptr,
                                             const int* __restrict__ col,
                                             const void* __restrict__ bias,
                                             const int* __restrict__ flag,
                                             float* __restrict__ Xout) {
    const int dt = *flag;
    const int lane = threadIdx.x & 31;
    const int node = blockIdx.x * 8 + (threadIdx.x >> 5);
    if (node >= NN) return;
    const int c0 = lane * 4;
    const size_t base = (size_t)node * 128 + c0;
    float4 h = *(const float4*)&H[base];
    float sn = dis[node], s2 = sn * sn;
    float4 acc;
    acc.x = fmaf(h.x, s2, ldf(bias, c0 + 0, dt));
    acc.y = fmaf(h.y, s2, ldf(bias, c0 + 1, dt));
    acc.z = fmaf(h.z, s2, ldf(bias, c0 + 2, dt));
    acc.w = fmaf(h.w, s2, ldf(bias, c0 + 3, dt));
    int e = rowptr[node], e1 = rowptr[node + 1];
    for (; e + 4 <= e1; e += 4) {
        int n0 = col[e], n1 = col[e + 1], n2 = col[e + 2], n3 = col[e + 3];
        float w0 = dis[n0] * sn, w1 = dis[n1] * sn, w2 = dis[n2] * sn, w3 = dis[n3] * sn;
        float4 h0 = *(const float4*)&H[(size_t)n0 * 128 + c0];
        float4 h1 = *(const float4*)&H[(size_t)n1 * 128 + c0];
        float4 h2 = *(const float4*)&H[(size_t)n2 * 128 + c0];
        float4 h3 = *(const float4*)&H[(size_t)n3 * 128 + c0];
        acc.x = fmaf(h0.x, w0, acc.x); acc.y = fmaf(h0.y, w0, acc.y);
        acc.z = fmaf(h0.z, w0, acc.z); acc.w = fmaf(h0.w, w0, acc.w);
        acc.x = fmaf(h1.x, w1, acc.x); acc.y = fmaf(h1.y, w1, acc.y);
        acc.z = fmaf(h1.z, w1, acc.z); acc.w = fmaf(h1.w, w1, acc.w);
        acc.x = fmaf(h2.x, w2, acc.x); acc.y = fmaf(h2.y, w2, acc.y);
        acc.z = fmaf(h2.z, w2, acc.z); acc.w = fmaf(h2.w, w2, acc.w);
        acc.x = fmaf(h3.x, w3, acc.x); acc.y = fmaf(h3.y, w3, acc.y);
        acc.z = fmaf(h3.z, w3, acc.z); acc.w = fmaf(h3.w, w3, acc.w);
    }
    for (; e < e1; ++e) {
        int nb = col[e];
        float w = dis[nb] * sn;
        float4 hn = *(const float4*)&H[(size_t)nb * 128 + c0];
        acc.x = fmaf(hn.x, w, acc.x); acc.y = fmaf(hn.y, w, acc.y);
        acc.z = fmaf(hn.z, w, acc.z); acc.w = fmaf(hn.w, w, acc.w);
    }
    f32x4 o = {tanhf(acc.x), tanhf(acc.y), tanhf(acc.z), tanhf(acc.w)};
    ntst4(&Xout[base], o);
}

// ------- fused layer-3 agg + tanh + dot W4, 4-way MLP -------
__global__ __launch_bounds__(256) void k_h4(const float* __restrict__ H3,
                                            const float* __restrict__ dis,
                                            const int* __restrict__ rowptr,
                                            const int* __restrict__ col,
                                            const void* __restrict__ b3,
                                            const void* __restrict__ W4,
                                            const int* __restrict__ flag,
                                            float* __restrict__ h4) {
    const int dt = *flag;
    const int lane = threadIdx.x & 31;
    const int node = blockIdx.x * 8 + (threadIdx.x >> 5);
    if (node >= NN) return;
    const int c0 = lane * 4;
    const size_t base = (size_t)node * 128 + c0;
    float4 h = *(const float4*)&H3[base];
    float sn = dis[node], s2 = sn * sn;
    float4 acc;
    acc.x = fmaf(h.x, s2, ldf(b3, c0 + 0, dt));
    acc.y = fmaf(h.y, s2, ldf(b3, c0 + 1, dt));
    acc.z = fmaf(h.z, s2, ldf(b3, c0 + 2, dt));
    acc.w = fmaf(h.w, s2, ldf(b3, c0 + 3, dt));
    int e = rowptr[node], e1 = rowptr[node + 1];
    for (; e + 4 <= e1; e += 4) {
        int n0 = col[e], n1 = col[e + 1], n2 = col[e + 2], n3 = col[e + 3];
        float w0 = dis[n0] * sn, w1 = dis[n1] * sn, w2 = dis[n2] * sn, w3 = dis[n3] * sn;
        float4 h0 = *(const float4*)&H3[(size_t)n0 * 128 + c0];
        float4 h1 = *(const float4*)&H3[(size_t)n1 * 128 + c0];
        float4 h2 = *(const float4*)&H3[(size_t)n2 * 128 + c0];
        float4 h3 = *(const float4*)&H3[(size_t)n3 * 128 + c0];
        acc.x = fmaf(h0.x, w0, acc.x); acc.y = fmaf(h0.y, w0, acc.y);
        acc.z = fmaf(h0.z, w0, acc.z); acc.w = fmaf(h0.w, w0, acc.w);
        acc.x = fmaf(h1.x, w1, acc.x); acc.y = fmaf(h1.y, w1, acc.y);
        acc.z = fmaf(h1.z, w1, acc.z); acc.w = fmaf(h1.w, w1, acc.w);
        acc.x = fmaf(h2.x, w2, acc.x); acc.y = fmaf(h2.y, w2, acc.y);
        acc.z = fmaf(h2.z, w2, acc.z); acc.w = fmaf(h2.w, w2, acc.w);
        acc.x = fmaf(h3.x, w3, acc.x); acc.y = fmaf(h3.y, w3, acc.y);
        acc.z = fmaf(h3.z, w3, acc.z); acc.w = fmaf(h3.w, w3, acc.w);
    }
    for (; e < e1; ++e) {
        int nb = col[e];
        float w = dis[nb] * sn;
        float4 hn = *(const float4*)&H3[(size_t)nb * 128 + c0];
        acc.x = fmaf(hn.x, w, acc.x); acc.y = fmaf(hn.y, w, acc.y);
        acc.z = fmaf(hn.z, w, acc.z); acc.w = fmaf(hn.w, w, acc.w);
    }
    float v = tanhf(acc.x) * ldf(W4, c0 + 0, dt) + tanhf(acc.y) * ldf(W4, c0 + 1, dt) +
              tanhf(acc.z) * ldf(W4, c0 + 2, dt) + tanhf(acc.w) * ldf(W4, c0 + 3, dt);
#pragma unroll
    for (int off = 16; off > 0; off >>= 1) v += __shfl_xor(v, off, 64);
    if (lane == 0) h4[node] = v;
}

__global__ void k_agg4(const float* __restrict__ h4, const float* __restrict__ dis,
                       const int* __restrict__ rowptr, const int* __restrict__ col,
                       const void* __restrict__ b4, const int* __restrict__ flag,
                       float* __restrict__ score) {
    const int dt = *flag;
    int i = blockIdx.x * 256 + threadIdx.x;
    if (i >= NN) return;
    float sn = dis[i];
    float acc = fmaf(h4[i] * sn, sn, ldf(b4, 0, dt));
    int e = rowptr[i], e1 = rowptr[i + 1];
    for (; e + 4 <= e1; e += 4) {
        int n0 = col[e], n1 = col[e + 1], n2 = col[e + 2], n3 = col[e + 3];
        float v0 = h4[n0] * dis[n0], v1 = h4[n1] * dis[n1];
        float v2 = h4[n2] * dis[n2], v3 = h4[n3] * dis[n3];
        acc = fmaf(v0 + v1 + v2 + v3, sn, acc);
    }
    for (; e < e1; ++e) {
        int nb = col[e];
        acc = fmaf(h4[nb] * dis[nb], sn, acc);
    }
    score[i] = tanhf(acc);
}

// ------------- radix-histogram top-64 per graph -------------
__global__ void k_hist(const float* __restrict__ score, const int* __restrict__ batch,
                       int* __restrict__ hist) {
    int i = blockIdx.x * 256 + threadIdx.x;
    if (i >= NN) return;
    unsigned u = fkey(score[i]);
    atomicAdd(&hist[batch[i] * 2048 + (u >> 21)], 1);
}

__global__ void k_thr(const int* __restrict__ hist, int* __restrict__ thr) {
    int g = threadIdx.x;
    if (g < GG) {
        int cum = 0, b = 0;
        for (int bin = 2047; bin >= 0; --bin) {
            cum += hist[g * 2048 + bin];
            if (cum >= 64) { b = bin; break; }
        }
        thr[g] = b;
    }
}

__global__ void k_collect(const float* __restrict__ score, const int* __restrict__ batch,
                          const int* __restrict__ thr, int* __restrict__ ccnt,
                          unsigned long long* __restrict__ cbuf) {
    int i = blockIdx.x * 256 + threadIdx.x;
    if (i >= NN) return;
    int g = batch[i];
    unsigned u = fkey(score[i]);
    if ((int)(u >> 21) >= thr[g]) {
        int p = atomicAdd(&ccnt[g], 1);
        if (p < CCAP)
            cbuf[(size_t)g * CCAP + p] =
                ((unsigned long long)u << 32) | (unsigned)(~(unsigned)i);
    }
}

__global__ __launch_bounds__(64) void k_top64(const unsigned long long* __restrict__ cbuf,
                                              const int* __restrict__ ccnt,
                                              int* __restrict__ sel) {
    __shared__ unsigned long long lds[4096];
    int g = blockIdx.x, t = threadIdx.x;
    int C = ccnt[g];
    if (C > CCAP) C = CCAP;
    const unsigned long long* src = cbuf + (size_t)g * CCAP;
    int CL = C < 4096 ? C : 4096;
    for (int i = t; i < CL; i += 64) lds[i] = src[i];
    __syncthreads();
    unsigned long long prev = ~0ULL;
    for (int k = 0; k < 64; ++k) {
        unsigned long long best = 0;
        for (int i = t; i < CL; i += 64) {
            unsigned long long v = lds[i];
            if (v < prev && v > best) best = v;
        }
        for (int i = 4096 + t; i < C; i += 64) {
            unsigned long long v = src[i];
            if (v < prev && v > best) best = v;
        }
#pragma unroll
        for (int off = 32; off > 0; off >>= 1) {
            unsigned long long o = __shfl_xor(best, off, 64);
            if (o > best) best = o;
        }
        if (t == 0)
            sel[g * 64 + k] = (best == 0) ? -1 : (int)~(unsigned)(best & 0xffffffffu);
        prev = best;
    }
}

// ------- recompute X1 rows for selected nodes (from x, W1, CSR) -------
__global__ __launch_bounds__(128) void k_x1sel(const void* __restrict__ x,
                                               const void* __restrict__ W1,
                                               const void* __restrict__ b1,
                                               const float* __restrict__ dis,
                                               const int* __restrict__ rowptr,
                                               const int* __restrict__ col,
                                               const int* __restrict__ sel,
                                               const int* __restrict__ flag,
                                               float* __restrict__ X1sel) {
    __shared__ float wl[100 * 128];
    __shared__ float xr[104];
    const int dt = *flag;
    int p = blockIdx.x, t = threadIdx.x;
    if (dt) {
        const float* Wf = (const float*)W1;
        for (int idx = t; idx < 100 * 128; idx += 128) wl[idx] = Wf[idx];
    } else {
        const unsigned short* Wb = (const unsigned short*)W1;
        for (int idx = t; idx < 100 * 128; idx += 128) wl[idx] = us2f(Wb[idx]);
    }
    int si = sel[p];
    __syncthreads();
    if (si < 0) { X1sel[p * 128 + t] = 0.f; return; }
    float sn = dis[si], s2 = sn * sn;
    for (int idx = t; idx < 100; idx += 128) xr[idx] = ldf(x, (long)si * 100 + idx, dt);
    __syncthreads();
    float h = 0.f;
    for (int k = 0; k < 100; ++k) h = fmaf(xr[k], wl[k * 128 + t], h);
    float acc = fmaf(h, s2, ldf(b1, t, dt));
    int e0 = rowptr[si], e1 = rowptr[si + 1];
    for (int e = e0; e < e1; ++e) {
        int nb = col[e];
        __syncthreads();
        for (int idx = t; idx < 100; idx += 128) xr[idx] = ldf(x, (long)nb * 100 + idx, dt);
        __syncthreads();
        h = 0.f;
        for (int k = 0; k < 100; ++k) h = fmaf(xr[k], wl[k * 128 + t], h);
        acc = fmaf(h, dis[nb] * sn, acc);
    }
    X1sel[p * 128 + t] = tanhf(acc);
}

// ------- recompute X3 rows for selected nodes (from H3, CSR) -------
__global__ __launch_bounds__(128) void k_x3sel(const float* __restrict__ H3,
                                               const void* __restrict__ b3,
                                               const float* __restrict__ dis,
                                               const int* __restrict__ rowptr,
                                               const int* __restrict__ col,
                                               const int* __restrict__ sel,
                                               const int* __restrict__ flag,
                                               float* __restrict__ X3sel) {
    const int dt = *flag;
    int p = blockIdx.x, t = threadIdx.x;
    int si = sel[p];
    if (si < 0) { X3sel[p * 128 + t] = 0.f; return; }
    float sn = dis[si], s2 = sn * sn;
    float acc = fmaf(H3[(size_t)si * 128 + t], s2, ldf(b3, t, dt));
    int e1 = rowptr[si + 1];
    for (int e = rowptr[si]; e < e1; ++e) {
        int nb = col[e];
        acc = fmaf(H3[(size_t)nb * 128 + t], dis[nb] * sn, acc);
    }
    X3sel[p * 128 + t] = tanhf(acc);
}

// -------- gather pooled row + conv5 (kernel=stride=385) + relu --------
__global__ __launch_bounds__(64) void k_gconv5(const int* __restrict__ sel,
                                               const float* __restrict__ X1sel,
                                               const float* __restrict__ X2,
                                               const float* __restrict__ X3sel,
                                               const float* __restrict__ score,
                                               const void* __restrict__ cw5,
                                               const void* __restrict__ cb5,
                                               const int* __restrict__ flag,
                                               float* __restrict__ h5) {
    __shared__ float feat[DCAT];
    const int dt = *flag;
    int g = blockIdx.x >> 6, t = blockIdx.x & 63;
    int p = g * 64 + t;
    int si = sel[p];
    for (int d = threadIdx.x; d < DCAT; d += 64) {
        float v = 0.f;
        if (si >= 0) {
            if (d < 128) v = X1sel[p * 128 + d];
            else if (d < 256) v = X2[(size_t)si * 128 + d - 128];
            else if (d < 384) v = X3sel[p * 128 + d - 256];
            else v = score[si];
        }
        feat[d] = v;
    }
    __syncthreads();
    int oc = threadIdx.x;
    float acc = ldf(cb5, oc, dt);
    if (dt) {
        const float* w = (const float*)cw5 + (size_t)oc * DCAT;
        for (int d = 0; d < DCAT; ++d) acc = fmaf(feat[d], w[d], acc);
    } else {
        const unsigned short* w = (const unsigned short*)cw5 + (size_t)oc * DCAT;
        for (int d = 0; d < DCAT; ++d) acc = fmaf(feat[d], us2f(w[d]), acc);
    }
    h5[(g * 64 + oc) * 64 + t] = fmaxf(acc, 0.f);
}

// -------- maxpool(2) + conv6 (64ch -> 128ch, k=5) + relu -> emb --------
__global__ __launch_bounds__(128) void k_conv6(const float* __restrict__ h5,
                                               const void* __restrict__ cw6,
                                               const void* __restrict__ cb6,
                                               const int* __restrict__ flag,
                                               float* __restrict__ emb) {
    __shared__ float hp[64][32];
    const int dt = *flag;
    int g = blockIdx.x;
    for (int idx = threadIdx.x; idx < 2048; idx += 128) {
        int ic = idx >> 5, u = idx & 31;
        float a = h5[g * 4096 + ic * 64 + 2 * u];
        float b = h5[g * 4096 + ic * 64 + 2 * u + 1];
        hp[ic][u] = fmaxf(a, b);
    }
    __syncthreads();
    int oc = threadIdx.x;
    float acc[28];
#pragma unroll
    for (int p = 0; p < 28; ++p) acc[p] = 0.f;
    for (int ic = 0; ic < 64; ++ic) {
        float w[5];
#pragma unroll
        for (int k = 0; k < 5; ++k) w[k] = ldf(cw6, (long)oc * 320 + ic * 5 + k, dt);
        float hv[32];
#pragma unroll
        for (int u = 0; u < 32; ++u) hv[u] = hp[ic][u];
#pragma unroll
        for (int p = 0; p < 28; ++p)
#pragma unroll
            for (int k = 0; k < 5; ++k) acc[p] = fmaf(hv[p + k], w[k], acc[p]);
    }
    float cb = ldf(cb6, oc, dt);
    for (int p = 0; p < 28; ++p)
        emb[g * 3584 + oc * 28 + p] = fmaxf(acc[p] + cb, 0.f);
}

// ---------------- FC layers ----------------
__global__ __launch_bounds__(256) void k_fc1(const float* __restrict__ emb,
                                             const void* __restrict__ fw1,
                                             const void* __restrict__ fb1,
                                             const int* __restrict__ flag,
                                             float* __restrict__ out128) {
    __shared__ float red[256];
    const int dt = *flag;
    int j = blockIdx.x;
    float acc = 0.f;
    if (dt) {
        const float* w = (const float*)fw1 + (size_t)j * 39424;
        for (int i = threadIdx.x; i < 39424; i += 256) acc = fmaf(emb[i], w[i], acc);
    } else {
        const unsigned short* w = (const unsigned short*)fw1 + (size_t)j * 39424;
        for (int i = threadIdx.x; i < 39424; i += 256) acc = fmaf(emb[i], us2f(w[i]), acc);
    }
    red[threadIdx.x] = acc;
    __syncthreads();
    for (int s = 128; s > 0; s >>= 1) {
        if (threadIdx.x < s) red[threadIdx.x] += red[threadIdx.x + s];
        __syncthreads();
    }
    if (threadIdx.x == 0) out128[j] = fmaxf(red[0] + ldf(fb1, j, dt), 0.f);
}

__global__ void k_fc2(const float* __restrict__ out128,
                      const void* __restrict__ fw2,
                      const void* __restrict__ fb2,
                      const int* __restrict__ flag,
                      void* __restrict__ outv) {
    const int dt = *flag;
    int c = threadIdx.x;
    if (c < 10) {
        float acc = ldf(fb2, c, dt);
        for (int j = 0; j < 128; ++j) acc = fmaf(out128[j], ldf(fw2, c * 128 + j, dt), acc);
        if (dt) ((float*)outv)[c] = acc;
        else ((__hip_bfloat16*)outv)[c] = __float2bfloat16(acc);
    }
}

extern "C" void kernel_launch(void* const* d_in, const int* in_sizes, int n_in,
                              void* d_out, int out_size, void* d_ws, size_t ws_size,
                              hipStream_t stream) {
    const void* x = d_in[0];
    const int* ei = (const int*)d_in[1];
    const int* batch = (const int*)d_in[2];
    const void* W1 = d_in[3];
    const void* b1 = d_in[4];
    const void* W2 = d_in[5];
    const void* b2 = d_in[6];
    const void* W3 = d_in[7];
    const void* b3 = d_in[8];
    const void* W4 = d_in[9];
    const void* b4 = d_in[10];
    const void* cw5 = d_in[11];
    const void* cb5 = d_in[12];
    const void* cw6 = d_in[13];
    const void* cb6 = d_in[14];
    const void* fw1 = d_in[15];
    const void* fb1 = d_in[16];
    const void* fw2 = d_in[17];
    const void* fb2 = d_in[18];

    // ---- workspace layout: H buffers 512B-aligned (gather rows = 4 cache lines) ----
    const size_t BIG = (size_t)NN * 128;
    float* f_A = (float*)(((size_t)d_ws + 511) & ~(size_t)511); // BIG (H1->H2->H3)
    float* f_B = f_A + BIG;                      // BIG  (X1 -> X2)
    float* f_dis = f_B + BIG;                    // NN
    float* f_score = f_dis + NN;                 // NN
    float* f_h4 = f_score + NN;                  // NN
    float* f_h5 = f_h4 + NN;                     // 45056
    float* f_emb = f_h5 + 45056;                 // 39424
    float* f_o128 = f_emb + 39424;               // 128
    float* f_X1sel = f_o128 + 128;               // 704*128
    float* f_X3sel = f_X1sel + 704 * 128;        // 704*128
    int* i_degcnt = (int*)(f_X3sel + 704 * 128); // NN   (zeroed region start)
    int* i_fill = i_degcnt + NN;                 // NN
    int* i_hist = i_fill + NN;                   // GG*2048
    int* i_ccnt = i_hist + GG * 2048;            // 16
    int* i_rowptr = i_ccnt + 16;                 // NN+1
    int* i_col = i_rowptr + NN + 1;              // EE
    int* i_bsum = i_col + EE;                    // 512
    int* i_thr = i_bsum + 512;                   // 16
    int* i_sel = i_thr + 16;                     // 704
    unsigned long long* c_buf =
        (unsigned long long*)(((size_t)(i_sel + 704) + 15) & ~(size_t)15); // GG*CCAP
    int* i_flag = (int*)(c_buf + (size_t)GG * CCAP); // 4 ints
    size_t need_bytes = (size_t)((char*)(i_flag + 4) - (char*)d_ws);

    if (ws_size < need_bytes) return;

    k_detect<<<1, 64, 0, stream>>>((const unsigned int*)x, i_flag);

    const int EB = (EE + 255) / 256;
    const int NB = (NN + 255) / 256;
    const int SB = (NN + 1023) / 1024;

    hipMemsetAsync(i_degcnt, 0, sizeof(int) * (2 * NN + GG * 2048 + 16), stream);

    k_deg<<<EB, 256, 0, stream>>>(ei, i_degcnt);
    k_dis<<<NB, 256, 0, stream>>>(i_degcnt, f_dis);
    k_scan1<<<SB, 256, 0, stream>>>(i_degcnt, i_rowptr + 1, i_bsum, NN);
    k_scan2<<<1, 512, 0, stream>>>(i_bsum, SB);
    k_scan3<<<NB, 256, 0, stream>>>(i_rowptr, i_bsum, NN);
    k_fill<<<EB, 256, 0, stream>>>(ei, i_rowptr, i_fill, i_col);

    const int MMB = NN / 128;  // 3125 (exact)
    const int AGB = NN / 8;    // 50000

    k_mm1<<<MMB, 256, 0, stream>>>(x, W1, i_flag, f_A);
    k_agg<<<AGB, 256, 0, stream>>>(f_A, f_dis, i_rowptr, i_col, b1, i_flag, f_B);
    k_mm<<<MMB, 256, 0, stream>>>(f_B, W2, i_flag, f_A);
    k_agg<<<AGB, 256, 0, stream>>>(f_A, f_dis, i_rowptr, i_col, b2, i_flag, f_B);
    k_mm<<<MMB, 256, 0, stream>>>(f_B, W3, i_flag, f_A);
    k_h4<<<AGB, 256, 0, stream>>>(f_A, f_dis, i_rowptr, i_col, b3, W4, i_flag, f_h4);
    k_agg4<<<NB, 256, 0, stream>>>(f_h4, f_dis, i_rowptr, i_col, b4, i_flag, f_score);

    k_hist<<<NB, 256, 0, stream>>>(f_score, batch, i_hist);
    k_thr<<<1, 64, 0, stream>>>(i_hist, i_thr);
    k_collect<<<NB, 256, 0, stream>>>(f_score, batch, i_thr, i_ccnt, c_buf);
    k_top64<<<GG, 64, 0, stream>>>(c_buf, i_ccnt, i_sel);

    k_x1sel<<<GG * 64, 128, 0, stream>>>(x, W1, b1, f_dis, i_rowptr, i_col, i_sel, i_flag, f_X1sel);
    k_x3sel<<<GG * 64, 128, 0, stream>>>(f_A, b3, f_dis, i_rowptr, i_col, i_sel, i_flag, f_X3sel);

    k_gconv5<<<GG * 64, 64, 0, stream>>>(i_sel, f_X1sel, f_B, f_X3sel, f_score, cw5, cb5, i_flag, f_h5);
    k_conv6<<<GG, 128, 0, stream>>>(f_h5, cw6, cb6, i_flag, f_emb);
    k_fc1<<<128, 256, 0, stream>>>(f_emb, fw1, fb1, i_flag, f_o128);
    k_fc2<<<1, 128, 0, stream>>>(f_o128, fw2, fb2, i_flag, d_out);

    (void)in_sizes; (void)n_in; (void)ws_size;
}